// Round 7
// baseline (419.841 us; speedup 1.0000x reference)
//
#include <hip/hip_runtime.h>

// ---------------------------------------------------------------------------
// Fused MultiHeadAttention forward for MI355X (gfx950).  Round 12.
//   B=4, S=2048, D_MODEL=1024, H=16, depth=64
// Round-12 changes:
//  - attn: 64-q-row blocks of 2 waves (was 128-q / 4 waves), grid 2048.
//    Per-wave code identical (32 q-rows, swapped 32x32x16 QK^T, in-reg P);
//    each wave stages 32 K'-rows + 32 V-rows (8 GLDS16).  Occupancy was
//    GRID-limited (1024 blocks = 4/CU = 50% cap, measured 33%); now 8
//    blocks/CU (135KB LDS), drains overlap across blocks.
//  - cvt_weights + cvt3 + mask_prepack merged into ONE prep dispatch
//    (branch by blockIdx range; bodies unchanged) - removes 2 launch gaps.
//  - gemm_qkv / gemm_wo unchanged (round-9 BK=64 versions).
// ---------------------------------------------------------------------------

typedef __bf16 bf16_t;
typedef __bf16 bf16x4 __attribute__((ext_vector_type(4)));
typedef __bf16 bf16x8 __attribute__((ext_vector_type(8)));
typedef float floatx2 __attribute__((ext_vector_type(2)));
typedef float floatx4 __attribute__((ext_vector_type(4)));
typedef float floatx16 __attribute__((ext_vector_type(16)));

#define DMODEL 1024
#define NHEAD  16
#define DEPTH  64
#define BATCH  4
#define SEQ    2048
#define MROWS  (BATCH * SEQ)   // 8192

// exp(s) = exp2(s*log2e); fold log2(e)/8 into Wq (and bq) so QK^T is exp2-ready
#define QSCALE 0.18033688011112042f

#define GLDS16(gaddr, laddr)                                                   \
  __builtin_amdgcn_global_load_lds(                                            \
      (__attribute__((address_space(1))) void*)(gaddr),                        \
      (__attribute__((address_space(3))) void*)(laddr), 16, 0, 0)

// ---------------------------------------------------------------------------
// prep: ONE dispatch doing (a) weight cvt (Wq pre-scaled), (b) activation
// cvt3, (c) mask bit-pack.  Branch by blockIdx range; bodies unchanged from
// round 11.
//   blocks [0,4096)      : weights  (4 x 1M elems, float4/thread)
//   blocks [4096,16384)  : cvt3     (3 x 8M elems, 8/thread)
//   blocks [16384,16640) : mask     (g = r&63, b = r>>6)
// ---------------------------------------------------------------------------
__global__ __launch_bounds__(256) void prep(
    const float* __restrict__ w0, const float* __restrict__ w1,
    const float* __restrict__ w2, const float* __restrict__ w3,
    bf16_t* __restrict__ wout,
    const float* __restrict__ qin, const float* __restrict__ kin,
    const float* __restrict__ vin, bf16_t* __restrict__ adst,
    const float* __restrict__ m, unsigned int* __restrict__ M32) {
  const int bid = blockIdx.x;
  if (bid < 4096) {
    // ---- weights ----
    const int n_per4 = (DMODEL * DMODEL) / 4;   // 2^18
    int idx = bid * 256 + threadIdx.x;
    int t = idx / n_per4;
    int e4 = idx - t * n_per4;
    const float* src = (t == 0) ? w0 : (t == 1) ? w1 : (t == 2) ? w2 : w3;
    const float sc = (t == 0) ? QSCALE : 1.0f;
    float4 v = ((const float4*)src)[e4];
    bf16_t* dst = wout + (size_t)t * (DMODEL * DMODEL) + (size_t)e4 * 4;
    dst[0] = (bf16_t)(v.x * sc); dst[1] = (bf16_t)(v.y * sc);
    dst[2] = (bf16_t)(v.z * sc); dst[3] = (bf16_t)(v.w * sc);
  } else if (bid < 16384) {
    // ---- cvt3 ----
    const size_t n8 = (size_t)MROWS * DMODEL / 8;   // 2^20
    size_t i = (size_t)(bid - 4096) * 256 + threadIdx.x;
    int t = (int)(i / n8);
    size_t e = i - (size_t)t * n8;
    const float* src = (t == 0) ? qin : (t == 1) ? kin : vin;
    const float4* s = (const float4*)(src + e * 8);
    float4 f0 = s[0], f1 = s[1];
    bf16x8 o;
    o[0] = (bf16_t)f0.x; o[1] = (bf16_t)f0.y; o[2] = (bf16_t)f0.z; o[3] = (bf16_t)f0.w;
    o[4] = (bf16_t)f1.x; o[5] = (bf16_t)f1.y; o[6] = (bf16_t)f1.z; o[7] = (bf16_t)f1.w;
    *(bf16x8*)(adst + i * 8) = o;
  } else {
    // ---- mask bit-pack (coalesced, round-11 body) ----
    __shared__ unsigned short Mb[32][132];
    const int r = bid - 16384;     // 0..255
    const int g = r & 63;
    const int b = r >> 6;
    const int tid = threadIdx.x;
    const int lane = tid & 63;
    const int w = tid >> 6;

    const float* base = m + ((size_t)b * SEQ + g * 32) * SEQ;
#pragma unroll
    for (int rr = 0; rr < 8; rr++) {
      const int rw = w * 8 + rr;
      const float* row = base + (size_t)rw * SEQ;
#pragma unroll
      for (int half = 0; half < 2; half++) {
        const int cg = lane + half * 64;
        unsigned int bits = 0;
#pragma unroll
        for (int j4 = 0; j4 < 4; j4++) {
          const float4 v = *(const float4*)(row + cg * 16 + j4 * 4);
          if (v.x == 0.f) bits |= 1u << (j4 * 4 + 0);
          if (v.y == 0.f) bits |= 1u << (j4 * 4 + 1);
          if (v.z == 0.f) bits |= 1u << (j4 * 4 + 2);
          if (v.w == 0.f) bits |= 1u << (j4 * 4 + 3);
        }
        Mb[rw][cg] = (unsigned short)bits;
      }
    }
    __syncthreads();

    const int q = lane & 31, hi = lane >> 5;
    unsigned int* dst = M32 + (size_t)(b * 64 + g) * 32 * 64 + lane;
#pragma unroll
    for (int ii = 0; ii < 8; ii++) {
      const int it = ii * 4 + w;
      unsigned int word = 0;
#pragma unroll
      for (int kb = 0; kb < 2; kb++)
#pragma unroll
        for (int c16 = 0; c16 < 2; c16++) {
          const unsigned int byte =
              ((unsigned int)Mb[q][it * 4 + kb * 2 + c16] >> (hi * 8)) & 0xFFu;
          word |= byte << (kb * 16 + c16 * 8);
        }
      dst[it * 64] = word;
    }
  }
}

// ---------------------------------------------------------------------------
// Merged QKV GEMM, BK=64 (round-9 version): z selects (input, weight, bias,
// output).  256 thr / 4 waves, 128x128 tile, two-barrier single-buffer
// staging, 8x global_load_lds(16B) per stage, 32 MFMA per stage.
// z<2 -> bf16 out [B,H,S,64] (Q,K); z==2 -> bf16 out [B,H,64,S] (V^T).
// ---------------------------------------------------------------------------
__global__ __launch_bounds__(256) void gemm_qkv(
    const bf16_t* __restrict__ Abf3, const bf16_t* __restrict__ Wbf,
    const float* __restrict__ bq, const float* __restrict__ bk,
    const float* __restrict__ bv, bf16_t* __restrict__ Qh,
    bf16_t* __restrict__ Kh, bf16_t* __restrict__ Vth) {
  __shared__ __align__(16) bf16_t As[128 * 64];   // 16 KB
  __shared__ __align__(16) bf16_t Bs[128 * 64];   // 16 KB
  const int K = DMODEL;
  const int tid = threadIdx.x;
  const int lane = tid & 63;
  const int w = tid >> 6;
  const int quad = lane >> 4;
  const int l16 = lane & 15;
  const int wm = w & 1, wn = w >> 1;
  const int z = blockIdx.z;

  const bf16_t* A = Abf3 + (size_t)z * MROWS * DMODEL;
  const bf16_t* Bt = Wbf + (size_t)z * DMODEL * DMODEL;
  const float* bias = (z == 0) ? bq : (z == 1) ? bk : bv;
  const float bias_scale = (z == 0) ? QSCALE : 1.0f;
  bf16_t* Ov = (z == 0) ? Qh : (z == 1) ? Kh : Vth;

  const int lin = blockIdx.x + 8 * blockIdx.y;   // (8,64) per z
  const int c = lin & 7;
  const int j = lin >> 3;            // 0..63
  const int n0 = (j & 7) * 128;
  const int m0 = ((j >> 3) * 8 + c) * 128;

  const int r8l = lane >> 3;
  const int c8l = (lane & 7) ^ r8l;
  const bf16_t* Ag = A + (size_t)(m0 + w * 32 + r8l) * K + c8l * 8;
  const bf16_t* Bg = Bt + (size_t)(n0 + w * 32 + r8l) * K + c8l * 8;
  char* AsB = (char*)As + (w * 32) * 128;
  char* BsB = (char*)Bs + (w * 32) * 128;

  floatx4 acc[4][4] = {};

  for (int kk = 0; kk < K; kk += 64) {
    __syncthreads();
#pragma unroll
    for (int cl = 0; cl < 4; cl++) {
      GLDS16(Ag + kk + (size_t)(cl * 8) * K, AsB + cl * 8 * 128);
      GLDS16(Bg + kk + (size_t)(cl * 8) * K, BsB + cl * 8 * 128);
    }
    __syncthreads();

#pragma unroll
    for (int kk2 = 0; kk2 < 2; kk2++) {
      bf16x8 af[4], bfr[4];
#pragma unroll
      for (int mi = 0; mi < 4; mi++) {
        const char* Arow = (const char*)As + (wm * 64 + mi * 16 + l16) * 128;
        af[mi] = *(const bf16x8*)(Arow + (((kk2 * 4 + quad) ^ (l16 & 7)) * 16));
      }
#pragma unroll
      for (int ni = 0; ni < 4; ni++) {
        const char* Brow = (const char*)Bs + (wn * 64 + ni * 16 + l16) * 128;
        bfr[ni] = *(const bf16x8*)(Brow + (((kk2 * 4 + quad) ^ (l16 & 7)) * 16));
      }
#pragma unroll
      for (int mi = 0; mi < 4; mi++)
#pragma unroll
        for (int ni = 0; ni < 4; ni++)
          acc[mi][ni] = __builtin_amdgcn_mfma_f32_16x16x32_bf16(af[mi], bfr[ni], acc[mi][ni], 0, 0, 0);
    }
  }

#pragma unroll
  for (int ni = 0; ni < 4; ni++) {
    const int col = n0 + wn * 64 + ni * 16 + l16;
    const float bvl = bias_scale * bias[col];
    const int hh = col >> 6, d = col & (DEPTH - 1);
#pragma unroll
    for (int mi = 0; mi < 4; mi++) {
#pragma unroll
      for (int r = 0; r < 4; r++) {
        const int row = m0 + wm * 64 + mi * 16 + quad * 4 + r;
        const float val = acc[mi][ni][r] + bvl;
        const int bb = row >> 11, s = row & (SEQ - 1);
        if (z != 2) {
          Ov[((((size_t)bb * NHEAD + hh) * SEQ + s) << 6) + d] = (bf16_t)val;
        } else {
          Ov[(((size_t)bb * NHEAD + hh) * DEPTH + d) * SEQ + s] = (bf16_t)val;
        }
      }
    }
  }
}

// ---------------------------------------------------------------------------
// Output-projection GEMM (A bf16, fp32 out [M,N]), BK=64.  Grid (8,64).
// ---------------------------------------------------------------------------
__global__ __launch_bounds__(256) void gemm_wo(
    const bf16_t* __restrict__ A, const bf16_t* __restrict__ Bt,
    const float* __restrict__ bias, float* __restrict__ Ov,
    int M, int N, int K) {
  __shared__ __align__(16) bf16_t As[128 * 64];
  __shared__ __align__(16) bf16_t Bs[128 * 64];
  const int tid = threadIdx.x;
  const int lane = tid & 63;
  const int w = tid >> 6;
  const int quad = lane >> 4;
  const int l16 = lane & 15;
  const int wm = w & 1, wn = w >> 1;

  const int lin = blockIdx.x + 8 * blockIdx.y;
  const int c = lin & 7;
  const int j = lin >> 3;
  const int n0 = (j & 7) * 128;
  const int m0 = ((j >> 3) * 8 + c) * 128;

  const int r8l = lane >> 3;
  const int c8l = (lane & 7) ^ r8l;
  const bf16_t* Ag = A + (size_t)(m0 + w * 32 + r8l) * K + c8l * 8;
  const bf16_t* Bg = Bt + (size_t)(n0 + w * 32 + r8l) * K + c8l * 8;
  char* AsB = (char*)As + (w * 32) * 128;
  char* BsB = (char*)Bs + (w * 32) * 128;

  floatx4 acc[4][4] = {};

  for (int kk = 0; kk < K; kk += 64) {
    __syncthreads();
#pragma unroll
    for (int cl = 0; cl < 4; cl++) {
      GLDS16(Ag + kk + (size_t)(cl * 8) * K, AsB + cl * 8 * 128);
      GLDS16(Bg + kk + (size_t)(cl * 8) * K, BsB + cl * 8 * 128);
    }
    __syncthreads();

#pragma unroll
    for (int kk2 = 0; kk2 < 2; kk2++) {
      bf16x8 af[4], bfr[4];
#pragma unroll
      for (int mi = 0; mi < 4; mi++) {
        const char* Arow = (const char*)As + (wm * 64 + mi * 16 + l16) * 128;
        af[mi] = *(const bf16x8*)(Arow + (((kk2 * 4 + quad) ^ (l16 & 7)) * 16));
      }
#pragma unroll
      for (int ni = 0; ni < 4; ni++) {
        const char* Brow = (const char*)Bs + (wn * 64 + ni * 16 + l16) * 128;
        bfr[ni] = *(const bf16x8*)(Brow + (((kk2 * 4 + quad) ^ (l16 & 7)) * 16));
      }
#pragma unroll
      for (int mi = 0; mi < 4; mi++)
#pragma unroll
        for (int ni = 0; ni < 4; ni++)
          acc[mi][ni] = __builtin_amdgcn_mfma_f32_16x16x32_bf16(af[mi], bfr[ni], acc[mi][ni], 0, 0, 0);
    }
  }

#pragma unroll
  for (int ni = 0; ni < 4; ni++) {
    const int col = n0 + wn * 64 + ni * 16 + l16;
    const float bv = bias[col];
#pragma unroll
    for (int mi = 0; mi < 4; mi++)
#pragma unroll
      for (int r = 0; r < 4; r++) {
        const int row = m0 + wm * 64 + mi * 16 + quad * 4 + r;
        Ov[(size_t)row * N + col] = acc[mi][ni][r] + bv;
      }
  }
}

// ---------------------------------------------------------------------------
// Attention, round 12: 64-q blocks, 2 waves; per-wave structure identical to
// round 9 (swapped 32x32x16 QK^T, in-register P, two-barrier staging,
// paired-float2 lsum + Lsm epilogue, sbfe mask).  Each wave stages 32 K'-rows
// (bit2<->3 permuted) + 32 V-rows = 8 GLDS16.  Grid (32,16,4), 128 thr.
// ---------------------------------------------------------------------------
__global__ __launch_bounds__(128, 4) void attn_kernel(
    const bf16_t* __restrict__ Qh, const bf16_t* __restrict__ Kh,
    const bf16_t* __restrict__ Vt, const unsigned int* __restrict__ M32,
    bf16_t* __restrict__ O) {
  const int lane = threadIdx.x & 63;
  const int w = __builtin_amdgcn_readfirstlane(threadIdx.x >> 6);  // 0..1
  const int l31 = lane & 31;
  const int hi = lane >> 5;

  const int lin = blockIdx.x + 32 * blockIdx.y + 512 * blockIdx.z;  // 0..2047
  const int x8 = lin & 7;
  const int kk = lin >> 3;              // 0..255
  const int qt = kk & 31;               // q-tile (64 rows)
  const int bh = ((kk >> 5) << 3) | x8; // (b,h) pair
  const int h = bh & 15;
  const int b = bh >> 4;
  const int q0 = qt * 64;

  const bf16_t* Qb = Qh + ((size_t)b * NHEAD + h) * SEQ * DEPTH;
  const bf16_t* Kb = Kh + ((size_t)b * NHEAD + h) * SEQ * DEPTH;
  const bf16_t* Vb = Vt + ((size_t)b * NHEAD + h) * DEPTH * SEQ;
  const unsigned int* Mw =
      M32 + ((size_t)b * 64 + (qt * 2 + w)) * 32 * 64 + lane;

  __shared__ __align__(16) bf16_t Ksm[64 * 64];   // [key'][depth], swizzled
  __shared__ __align__(16) bf16_t Vsm[64 * 64];   // [depth][key], swizzled
  __shared__ float Lsm[2][32];

  // Staging: LDS dest linear; global K row is the bit2<->3-permuted key;
  // col chunk XOR-swizzled: LDS[row][c] = G[s(row)][c ^ (row&7)].
  const int r8 = lane >> 3;
  const int c8 = (lane & 7) ^ r8;
  const bf16_t* Kg[4];
#pragma unroll
  for (int cl = 0; cl < 4; cl++) {
    const int i = w * 32 + cl * 8 + r8;
    const int lo = i & 31;
    const int s = (i & 32) | ((lo & ~12) | ((lo & 4) << 1) | ((lo & 8) >> 1));
    Kg[cl] = Kb + (size_t)s * DEPTH + c8 * 8;
  }
  const bf16_t* Vg = Vb + (size_t)(w * 32 + r8) * SEQ + c8 * 8;
  char* KsB = (char*)Ksm + (w * 32) * 128;
  char* VsB = (char*)Vsm + (w * 32) * 128;

  // Q fragments (B-operand): aq[t] = Q[q][t*16 + hi*8 + j], q = q0+w*32+l31
  bf16x8 aq[4];
  {
    const bf16_t* qp = Qb + (size_t)(q0 + w * 32 + l31) * DEPTH + hi * 8;
#pragma unroll
    for (int t = 0; t < 4; t++) aq[t] = *(const bf16x8*)(qp + t * 16);
  }

  floatx16 acco[2] = {};
  floatx2 l2 = {0.f, 0.f};
  const int kxor = l31 & 7;

  for (int it = 0; it < SEQ / 64; ++it) {
    const int sk = it * 64;
    const unsigned int mword = Mw[it * 64];   // prefetch before barriers
    __syncthreads();   // prior iteration's LDS reads complete
#pragma unroll
    for (int cl = 0; cl < 4; cl++)
      GLDS16(Kg[cl] + (size_t)sk * DEPTH, KsB + cl * 8 * 128);
#pragma unroll
    for (int cl = 0; cl < 4; cl++)
      GLDS16(Vg + sk + (size_t)(cl * 8) * SEQ, VsB + cl * 8 * 128);
    __syncthreads();   // vmcnt(0) drain: staged K/V visible

#pragma unroll
    for (int kb = 0; kb < 2; kb++) {
      // ---- QK^T: S^T tile, A = K' (permuted rows), B = Q ----
      floatx16 s = {};
      const char* Krow = (const char*)Ksm + (kb * 32 + l31) * 128;
#pragma unroll
      for (int t = 0; t < 4; t++) {
        bf16x8 kf = *(const bf16x8*)(Krow + (((2 * t + hi) ^ kxor) * 16));
        s = __builtin_amdgcn_mfma_f32_32x32x16_bf16(kf, aq[t], s, 0, 0, 0);
      }
      // ---- exp2, keep-bit mask (sbfe); P stays in registers ----
      float pv[16];
#pragma unroll
      for (int r = 0; r < 16; r++) {
        float e = __builtin_amdgcn_exp2f(s[r]);
        const int km = __builtin_amdgcn_sbfe((int)mword, kb * 16 + r, 1);
        pv[r] = __int_as_float(__float_as_int(e) & km);
      }
      // ---- paired row-sum (v_pk_add_f32) ----
#pragma unroll
      for (int r = 0; r < 8; r++)
        l2 += (floatx2){pv[2 * r], pv[2 * r + 1]};
      // ---- PV: A-frag m (= kb*2+mh) is pv[8*mh .. 8*mh+7] packed ----
#pragma unroll
      for (int mh = 0; mh < 2; mh++) {
        bf16x8 pa;
#pragma unroll
        for (int j2 = 0; j2 < 8; j2++) pa[j2] = (bf16_t)pv[mh * 8 + j2];
        const int m = kb * 2 + mh;
#pragma unroll
        for (int n = 0; n < 2; n++) {
          const char* Vrow = (const char*)Vsm + (n * 32 + l31) * 128;
          bf16x8 vf = *(const bf16x8*)(Vrow + (((2 * m + hi) ^ kxor) * 16));
          acco[n] = __builtin_amdgcn_mfma_f32_32x32x16_bf16(pa, vf, acco[n], 0, 0, 0);
        }
      }
    }
  }

  // ---- epilogue: denominator and store ----
  float lsum = l2.x + l2.y;
  float tot = lsum + __shfl_xor(lsum, 32);
  if (lane < 32) Lsm[w][l31] = __frcp_rn(tot);
  __syncthreads();

#pragma unroll
  for (int r = 0; r < 16; r++) {
    const int qr = (r & 3) + 8 * (r >> 2) + 4 * hi;   // true q-row (C layout)
    const float inv = Lsm[w][qr];
    const size_t srow = (size_t)q0 + w * 32 + qr;
#pragma unroll
    for (int n = 0; n < 2; n++) {
      const int d = h * DEPTH + n * 32 + l31;
      O[((size_t)b * SEQ + srow) * DMODEL + d] = (bf16_t)(acco[n][r] * inv);
    }
  }
}

// ---------------------------------------------------------------------------
extern "C" void kernel_launch(void* const* d_in, const int* in_sizes, int n_in,
                              void* d_out, int out_size, void* d_ws, size_t ws_size,
                              hipStream_t stream) {
  const float* q_in = (const float*)d_in[0];
  const float* k_in = (const float*)d_in[1];
  const float* v_in = (const float*)d_in[2];
  const float* m_in = (const float*)d_in[3];
  const float* Wq = (const float*)d_in[4];
  const float* bq = (const float*)d_in[5];
  const float* Wk = (const float*)d_in[6];
  const float* bk = (const float*)d_in[7];
  const float* Wv = (const float*)d_in[8];
  const float* bv = (const float*)d_in[9];
  const float* Wo = (const float*)d_in[10];
  const float* bo = (const float*)d_in[11];

  // workspace layout:
  //   [0,   8MB) : bf16 weights Wq|Wk|Wv|Wo
  //   [8,  56MB) : Abf3 (3 x 16MB bf16 activations); first 16MB reused as
  //                Obuf after the QKV GEMMs complete (stream-ordered)
  //   [56, 72MB) : Qh  bf16 [B,H,S,64]
  //   [72, 88MB) : Kh  bf16 [B,H,S,64]
  //   [88,104MB) : Vth bf16 [B,H,64,S]
  //   [104,106MB): M32 keep-bit words
  char* ws = (char*)d_ws;
  const size_t MB = 1024 * 1024;
  bf16_t* wbf  = (bf16_t*)ws;
  bf16_t* Abf3 = (bf16_t*)(ws + 8 * MB);
  bf16_t* Obuf = (bf16_t*)(ws + 8 * MB);   // aliases Abf3[0] (safe: QKV done)
  bf16_t* Qh   = (bf16_t*)(ws + 56 * MB);
  bf16_t* Kh   = (bf16_t*)(ws + 72 * MB);
  bf16_t* Vth  = (bf16_t*)(ws + 88 * MB);
  unsigned int* M32 = (unsigned int*)(ws + 104 * MB);

  prep<<<16640, 256, 0, stream>>>(Wq, Wk, Wv, Wo, wbf,
                                  q_in, k_in, v_in, Abf3, m_in, M32);

  dim3 gqkv(8, 64, 3);
  gemm_qkv<<<gqkv, 256, 0, stream>>>(Abf3, wbf, bq, bk, bv, Qh, Kh, Vth);

  dim3 ga(32, NHEAD, BATCH);  // (32,16,4) x 128 thr
  attn_kernel<<<ga, 128, 0, stream>>>(Qh, Kh, Vth, M32, Obuf);

  dim3 gg(8, 64);
  gemm_wo<<<gg, 256, 0, stream>>>(
      Obuf, wbf + 3 * (size_t)DMODEL * DMODEL, bo, (float*)d_out,
      MROWS, DMODEL, DMODEL);
}